// Round 4
// baseline (55.976 us; speedup 1.0000x reference)
//
#include <hip/hip_runtime.h>
#include <math.h>

#define NCLS   20
#define MCELLS 49
#define FEAT   30
#define ITEMF  1470   // MCELLS * FEAT

typedef unsigned long long u64;
typedef unsigned int u32;
typedef float f32x4 __attribute__((ext_vector_type(4)));

__device__ __forceinline__ float bcastf(float v, int l) {
  return __int_as_float(__builtin_amdgcn_readlane(__float_as_int(v), l));
}
__device__ __forceinline__ int bcasti(int v, int l) {
  return __builtin_amdgcn_readlane(v, l);
}
__device__ __forceinline__ void nts(float* p, float v) { __builtin_nontemporal_store(v, p); }

__global__ __launch_bounds__(128) void yolo_post(const float* __restrict__ x,
                                                 float* __restrict__ out,
                                                 int N) {
  const int wave = threadIdx.x >> 6;       // 0..1
  const int lane = threadIdx.x & 63;
  const int n0 = (blockIdx.x * 2 + wave) * 2;   // this wave owns items n0, n0+1

  __shared__ float ldsAll[2][2][ITEMF];

  if (n0 >= N) return;  // wave-uniform exit; no block-wide barriers used
  const bool has1 = (n0 + 1) < N;
  const int nn[2] = { n0, has1 ? n0 + 1 : n0 };
  float* const LL[2] = { ldsAll[wave][0], ldsAll[wave][1] };

  // ---- stage both items to LDS (coalesced float2 loads, 24 loads in flight) ----
#pragma unroll
  for (int t = 0; t < 2; ++t) {
    const float2* src = (const float2*)(x) + (size_t)nn[t] * (ITEMF / 2);
    float2* Ld = (float2*)LL[t];
#pragma unroll
    for (int i = 0; i < 12; ++i) {
      int idx = lane + i * 64;
      if (idx < ITEMF / 2) Ld[idx] = src[idx];
    }
  }
  __threadfence_block();  // order LDS writes before cross-lane reads (wave-synchronous)

  // ---- output section pointers (flat concat in return order) ----
  const size_t NM = (size_t)N * MCELLS;
  float* out0 = out;              // class_logits  N*M*20
  float* out1 = out0 + NM * 20;   // yolo_bboxes   N*M*5
  float* out2 = out1 + NM * 5;    // boxes         N*M*4
  float* out3 = out2 + NM * 4;    // scores        N*M
  float* out4 = out3 + NM;        // labels        N*M
  float* out5 = out4 + NM;        // keep_mask     N*M
  float* out6 = out5 + NM;        // reserve_mask  N*M

  // ---- class logits copy: LDS -> global, coalesced NT stores ----
#pragma unroll
  for (int t = 0; t < 2; ++t) {
    if (t == 1 && !has1) break;
    float* dst = out0 + (size_t)nn[t] * (MCELLS * NCLS);
    const float* L = LL[t];
#pragma unroll
    for (int i = 0; i < 16; ++i) {
      int idx = lane + i * 64;
      if (idx < MCELLS * NCLS) {
        int c = idx / NCLS;
        int k = idx - c * NCLS;
        nts(dst + idx, L[c * FEAT + k]);
      }
    }
  }

  // ---- per-cell compute (lane m = cell m), both items ----
  const int m = lane;
  const bool cellv = (m < MCELLS);
  const int base = m * FEAT;

  int   labi[2];
  float conf[2];
  float x0[2], y0[2], x1[2], y1[2];
  bool  reserve[2];

#pragma unroll
  for (int t = 0; t < 2; ++t) {
    labi[t] = 0; conf[t] = 0.f;
    x0[t] = y0[t] = x1[t] = y1[t] = 0.f;
    reserve[t] = false;
    if (cellv) {
      const float2* Lp = (const float2*)(LL[t] + base);  // 8B-aligned (m*120B)
      // label = argmax over 20 logits (first-max), == argmax(softmax)
      float bestv; int bl = 0;
      {
        float2 p = Lp[0];
        bestv = p.x;
        if (p.y > bestv) { bestv = p.y; bl = 1; }
#pragma unroll
        for (int j = 1; j < 10; ++j) {
          float2 q = Lp[j];
          if (q.x > bestv) { bestv = q.x; bl = 2 * j; }
          if (q.y > bestv) { bestv = q.y; bl = 2 * j + 1; }
        }
      }
      labi[t] = bl;

      // bbox block: elements 20..29 via 5 float2
      float2 q0 = Lp[10], q1 = Lp[11], q2 = Lp[12], q3 = Lp[13], q4 = Lp[14];
      float c0 = q2.x, c1 = q4.y;
      bool sel1 = (c1 > c0);             // argmax first-max tie rule
      float bx = sel1 ? q2.y : q0.x;
      float by = sel1 ? q3.x : q0.y;
      float bw = sel1 ? q3.y : q1.x;
      float bh = sel1 ? q4.x : q1.y;
      float cf = sel1 ? c1 : c0;
      conf[t] = cf;

      float xg = (float)(m % 7), yg = (float)(m / 7);
      float cx = (bx + xg) / 7.0f, cy = (by + yg) / 7.0f;
      float hw = bw * 0.5f, hh = bh * 0.5f;
      x0[t] = fminf(fmaxf((cx - hw) * 448.0f, 0.f), 448.f);
      y0[t] = fminf(fmaxf((cy - hh) * 448.0f, 0.f), 448.f);
      x1[t] = fminf(fmaxf((cx + hw) * 448.0f, 0.f), 448.f);
      y1[t] = fminf(fmaxf((cy + hh) * 448.0f, 0.f), 448.f);
      reserve[t] = (cf > 0.1f);

      if (t == 0 || has1) {
        size_t ci = (size_t)nn[t] * MCELLS + m;
        float* yb = out1 + ci * 5;
        nts(yb + 0, bx); nts(yb + 1, by); nts(yb + 2, bw); nts(yb + 3, bh); nts(yb + 4, cf);
        f32x4 bx4 = { x0[t], y0[t], x1[t], y1[t] };
        __builtin_nontemporal_store(bx4, (f32x4*)(out2 + ci * 4));
        nts(out3 + ci, cf);
        nts(out4 + ci, (float)labi[t]);
        nts(out6 + ci, reserve[t] ? 1.0f : 0.0f);
      }
    }
  }

  // ================= NMS (both items interleaved) =================
  // Cross-class IoU is exactly 0 under the reference's class-offset scheme,
  // so the global greedy scan == independent per-class greedy scans.
  u64 key[2];
#pragma unroll
  for (int t = 0; t < 2; ++t) {
    if (cellv && reserve[t]) {
      u32 sb = __float_as_uint(conf[t]);        // conf in [0,1): monotone bits
      u32 inv = 0x7FFFFFFFu - sb;               // descending score -> ascending field
      key[t] = ((u64)labi[t] << 37) | ((u64)inv << 6) | (u64)lane;
    } else {
      key[t] = ~0ull;
    }
  }

  // bitonic sort, 64 lanes, ascending — two items interleaved for ILP
#pragma unroll
  for (int k = 2; k <= 64; k <<= 1) {
#pragma unroll
    for (int j = k >> 1; j >= 1; j >>= 1) {
      u64 ok0 = __shfl(key[0], lane ^ j);
      u64 ok1 = __shfl(key[1], lane ^ j);
      bool lower = (lane & j) == 0;
      bool asc = (lane & k) == 0;
      if ((key[0] > ok0) == (lower == asc)) key[0] = ok0;
      if ((key[1] > ok1) == (lower == asc)) key[1] = ok1;
    }
  }

  int  sid[2]; int slab[2];
  float gx0[2], gy0[2], gx1[2], gy1[2], garea[2];
#pragma unroll
  for (int t = 0; t < 2; ++t) {
    sid[t]  = (int)(key[t] & 63);
    slab[t] = (int)((key[t] >> 37) & 31);   // 31 for invalid
    gx0[t] = __shfl(x0[t], sid[t]); gy0[t] = __shfl(y0[t], sid[t]);
    gx1[t] = __shfl(x1[t], sid[t]); gy1[t] = __shfl(y1[t], sid[t]);
    garea[t] = fmaxf(gx1[t] - gx0[t], 0.f) * fmaxf(gy1[t] - gy0[t], 0.f);
  }

  // parallel suppression-row masks via rotations (same-label runs are contiguous)
  u64 rowm[2] = { 0ull, 0ull };
  for (int d = 1; d < MCELLS; ++d) {
    int srcl = (lane + d) & 63;
    bool mt[2]; u64 any[2];
#pragma unroll
    for (int t = 0; t < 2; ++t) {
      int plab = __shfl(slab[t], srcl);
      mt[t] = (plab == slab[t]) && (slab[t] != 31) && (lane + d < 64);
      any[t] = __ballot(mt[t]);
    }
    if ((any[0] | any[1]) == 0ull) break;
#pragma unroll
    for (int t = 0; t < 2; ++t) {
      if (any[t]) {
        float px0 = __shfl(gx0[t], srcl), py0 = __shfl(gy0[t], srcl);
        float px1 = __shfl(gx1[t], srcl), py1 = __shfl(gy1[t], srcl);
        float pa  = __shfl(garea[t], srcl);
        float iw = fmaxf(fminf(px1, gx1[t]) - fmaxf(px0, gx0[t]), 0.f);
        float ih = fmaxf(fminf(py1, gy1[t]) - fmaxf(py0, gy0[t]), 0.f);
        float inter = iw * ih;
        float uni = pa + garea[t] - inter;
        bool ok = mt[t] && (inter > 0.7f * fmaxf(uni, 1e-9f));
        rowm[t] |= ok ? (1ull << srcl) : 0ull;
      }
    }
  }

  // serial greedy scans — SALU bit ops, 2 readlanes per kept box, interleaved
  int V0 = __popcll(__ballot(key[0] != ~0ull));
  int V1 = __popcll(__ballot(key[1] != ~0ull));
  int rlo0 = (int)(rowm[0] & 0xFFFFFFFFull), rhi0 = (int)(rowm[0] >> 32);
  int rlo1 = (int)(rowm[1] & 0xFFFFFFFFull), rhi1 = (int)(rowm[1] >> 32);
  u64 supp0 = 0, keep0 = 0, supp1 = 0, keep1 = 0;
  int Vmax = V0 > V1 ? V0 : V1;
  for (int i = 0; i < Vmax; ++i) {
    if (i < V0 && !((supp0 >> i) & 1ull)) {
      keep0 |= 1ull << i;
      supp0 |= ((u64)(u32)bcasti(rhi0, i) << 32) | (u32)bcasti(rlo0, i);
    }
    if (i < V1 && !((supp1 >> i) & 1ull)) {
      keep1 |= 1ull << i;
      supp1 |= ((u64)(u32)bcasti(rhi1, i) << 32) | (u32)bcasti(rlo1, i);
    }
  }

  // scatter keep bit (sorted lane -> original cell lane) via ds_permute
  int kb0 = (int)((keep0 >> lane) & 1ull);
  int kb1 = (int)((keep1 >> lane) & 1ull);
  int kf0 = __builtin_amdgcn_ds_permute(sid[0] << 2, __float_as_int((float)kb0));
  int kf1 = __builtin_amdgcn_ds_permute(sid[1] << 2, __float_as_int((float)kb1));
  if (cellv) {
    nts(out5 + (size_t)nn[0] * MCELLS + m, __int_as_float(kf0));
    if (has1) nts(out5 + (size_t)nn[1] * MCELLS + m, __int_as_float(kf1));
  }
}

extern "C" void kernel_launch(void* const* d_in, const int* in_sizes, int n_in,
                              void* d_out, int out_size, void* d_ws, size_t ws_size,
                              hipStream_t stream) {
  const float* x = (const float*)d_in[0];
  float* out = (float*)d_out;
  int N = in_sizes[0] / ITEMF;
  int itemsPerBlock = 4;                      // 2 waves x 2 items
  int grid = (N + itemsPerBlock - 1) / itemsPerBlock;
  yolo_post<<<grid, 128, 0, stream>>>(x, out, N);
}

// Round 5
// 43.089 us; speedup vs baseline: 1.2991x; 1.2991x over previous
//
#include <hip/hip_runtime.h>
#include <math.h>

#define NCLS   20
#define MCELLS 49
#define FEAT   30
#define ITEMF  1470   // MCELLS * FEAT

typedef unsigned long long u64;
typedef unsigned int u32;
typedef float f32x4 __attribute__((ext_vector_type(4)));

__device__ __forceinline__ int bcasti(int v, int l) {
  return __builtin_amdgcn_readlane(v, l);
}
__device__ __forceinline__ void nts(float* p, float v) { __builtin_nontemporal_store(v, p); }

__global__ __launch_bounds__(256) void yolo_post(const float* __restrict__ x,
                                                 float* __restrict__ out,
                                                 int N) {
  const int wave = threadIdx.x >> 6;
  const int lane = threadIdx.x & 63;
  const int n = blockIdx.x * 4 + wave;
  if (n >= N) return;   // wave-uniform exit; no LDS, no barriers

  const float* item = x + (size_t)n * ITEMF;

  // ---- output section pointers (flat concat in return order) ----
  const size_t NM = (size_t)N * MCELLS;
  float* out0 = out;              // class_logits  N*M*20
  float* out1 = out0 + NM * 20;   // yolo_bboxes   N*M*5
  float* out2 = out1 + NM * 5;    // boxes         N*M*4
  float* out3 = out2 + NM * 4;    // scores        N*M
  float* out4 = out3 + NM;        // labels        N*M
  float* out5 = out4 + NM;        // keep_mask     N*M
  float* out6 = out5 + NM;        // reserve_mask  N*M

  const int m = lane;
  const bool cellv = (m < MCELLS);

  // ---- per-lane AoS loads: lane m owns cell m's 30 floats (15x float2, 8B-aligned) ----
  float2 v[15];
  if (cellv) {
    const float2* Lp = (const float2*)(item + m * FEAT);
#pragma unroll
    for (int j = 0; j < 15; ++j) v[j] = Lp[j];
  } else {
#pragma unroll
    for (int j = 0; j < 15; ++j) v[j] = make_float2(0.f, 0.f);
  }

  // ---- class logits copy: global->global gather (reads are L1/L2 hits), NT stores ----
  {
    float* dst = out0 + (size_t)n * (MCELLS * NCLS);
#pragma unroll
    for (int i = 0; i < 16; ++i) {
      int idx = lane + i * 64;
      if (idx < MCELLS * NCLS) {
        int c = idx / NCLS;
        int k = idx - c * NCLS;
        nts(dst + idx, item[c * FEAT + k]);
      }
    }
  }

  // ---- per-cell compute ----
  int   labi = 0;
  float conf = 0.f;
  float x0 = 0.f, y0 = 0.f, x1 = 0.f, y1 = 0.f;
  bool  reserve = false;

  if (cellv) {
    // label = argmax over 20 logits (first-max), == argmax(softmax)
    float bestv = v[0].x;
    if (v[0].y > bestv) { bestv = v[0].y; labi = 1; }
#pragma unroll
    for (int j = 1; j < 10; ++j) {
      if (v[j].x > bestv) { bestv = v[j].x; labi = 2 * j; }
      if (v[j].y > bestv) { bestv = v[j].y; labi = 2 * j + 1; }
    }

    // bbox block elems 20..29: v[10].x=bx0 .y=by0 v[11].x=bw0 .y=bh0 v[12].x=c0
    //                          v[12].y=bx1 v[13].x=by1 .y=bw1 v[14].x=bh1 .y=c1
    float c0 = v[12].x, c1 = v[14].y;
    bool sel1 = (c1 > c0);             // argmax first-max tie rule
    float bx = sel1 ? v[12].y : v[10].x;
    float by = sel1 ? v[13].x : v[10].y;
    float bw = sel1 ? v[13].y : v[11].x;
    float bh = sel1 ? v[14].x : v[11].y;
    conf = sel1 ? c1 : c0;

    float xg = (float)(m % 7), yg = (float)(m / 7);
    float cx = (bx + xg) / 7.0f, cy = (by + yg) / 7.0f;
    float hw = bw * 0.5f, hh = bh * 0.5f;
    x0 = fminf(fmaxf((cx - hw) * 448.0f, 0.f), 448.f);
    y0 = fminf(fmaxf((cy - hh) * 448.0f, 0.f), 448.f);
    x1 = fminf(fmaxf((cx + hw) * 448.0f, 0.f), 448.f);
    y1 = fminf(fmaxf((cy + hh) * 448.0f, 0.f), 448.f);
    reserve = (conf > 0.1f);

    size_t ci = (size_t)n * MCELLS + m;
    float* yb = out1 + ci * 5;
    nts(yb + 0, bx); nts(yb + 1, by); nts(yb + 2, bw); nts(yb + 3, bh); nts(yb + 4, conf);
    f32x4 bx4 = { x0, y0, x1, y1 };
    __builtin_nontemporal_store(bx4, (f32x4*)(out2 + ci * 4));
    nts(out3 + ci, conf);
    nts(out4 + ci, (float)labi);
    nts(out6 + ci, reserve ? 1.0f : 0.0f);
  }

  // ================= NMS =================
  // Cross-class IoU is exactly 0 under the reference's class-offset scheme,
  // so the global greedy scan == independent per-class greedy scans.
  // Sort by (label asc, score desc, idx asc) via a single u64 key; invalid -> ~0.
  u64 key;
  if (cellv && reserve) {
    u32 sb = __float_as_uint(conf);            // conf in (0.1,1): monotone bits
    u32 inv = 0x7FFFFFFFu - sb;                // descending score -> ascending field
    key = ((u64)labi << 37) | ((u64)inv << 6) | (u64)lane;
  } else {
    key = ~0ull;
  }

  // bitonic sort, 64 lanes, ascending
#pragma unroll
  for (int k = 2; k <= 64; k <<= 1) {
#pragma unroll
    for (int j = k >> 1; j >= 1; j >>= 1) {
      u64 ok = __shfl(key, lane ^ j);
      bool lower = (lane & j) == 0;
      bool asc = (lane & k) == 0;
      if ((key > ok) == (lower == asc)) key = ok;
    }
  }

  const int sid  = (int)(key & 63);
  const int slab = (int)((key >> 37) & 31);   // 31 for invalid

  // gather sorted coords
  float gx0 = __shfl(x0, sid), gy0 = __shfl(y0, sid);
  float gx1 = __shfl(x1, sid), gy1 = __shfl(y1, sid);
  float garea = fmaxf(gx1 - gx0, 0.f) * fmaxf(gy1 - gy0, 0.f);

  // max same-class run length (runs are contiguous after the sort) -> rotation bound.
  // One ballot + clz/ctz + 6-step shuffle max, instead of a ballot per rotation.
  {
  }
  int prevlab = __shfl(slab, (lane + 63) & 63);
  bool rstart = (lane == 0) || (prevlab != slab);
  u64 S = __ballot(rstart);                       // bit 0 always set
  u64 le_mask = (lane == 63) ? ~0ull : ((2ull << lane) - 1ull);
  int st = 63 - __builtin_clzll(S & le_mask);     // my run's start lane
  u64 gt = (lane == 63) ? 0ull : (S >> (lane + 1));
  int nxt = gt ? (lane + 1 + (int)__builtin_ctzll(gt)) : 64;
  int rl = (slab != 31) ? (nxt - st) : 1;
#pragma unroll
  for (int d2 = 1; d2 < 64; d2 <<= 1) {
    int o = __shfl_xor(rl, d2);
    rl = rl > o ? rl : o;
  }
  const int Dmax = __builtin_amdgcn_readfirstlane(rl);

  // parallel suppression-row masks via rotations, ballot-free
  u64 rowm = 0;
  for (int d = 1; d < Dmax; ++d) {
    int srcl = (lane + d) & 63;
    int plab = __shfl(slab, srcl);
    float px0 = __shfl(gx0, srcl), py0 = __shfl(gy0, srcl);
    float px1 = __shfl(gx1, srcl), py1 = __shfl(gy1, srcl);
    float pa  = __shfl(garea, srcl);
    bool match = (plab == slab) && (slab != 31) && (lane + d < 64);
    float iw = fmaxf(fminf(px1, gx1) - fmaxf(px0, gx0), 0.f);
    float ih = fmaxf(fminf(py1, gy1) - fmaxf(py0, gy0), 0.f);
    float inter = iw * ih;
    float uni = pa + garea - inter;
    bool ok = match && (inter > 0.7f * fmaxf(uni, 1e-9f));
    rowm |= ok ? (1ull << srcl) : 0ull;
  }

  // greedy scan over sorted order, skipping suppressed via ctz (iters = #kept)
  int V = __popcll(__ballot(key != ~0ull));       // valids occupy lanes 0..V-1
  int rlo = (int)(rowm & 0xFFFFFFFFull), rhi = (int)(rowm >> 32);
  u64 remaining = (V >= 64) ? ~0ull : ((1ull << V) - 1ull);
  u64 keep = 0;
  while (remaining) {
    int i = (int)__builtin_ctzll(remaining);
    keep |= 1ull << i;
    u64 rm = ((u64)(u32)bcasti(rhi, i) << 32) | (u32)bcasti(rlo, i);
    remaining &= ~(rm | (1ull << i));
  }

  // scatter keep bit (sorted lane -> original cell lane) via ds_permute
  int kb = (int)((keep >> lane) & 1ull);
  int kf = __builtin_amdgcn_ds_permute(sid << 2, __float_as_int((float)kb));
  if (cellv) nts(out5 + (size_t)n * MCELLS + m, __int_as_float(kf));
}

extern "C" void kernel_launch(void* const* d_in, const int* in_sizes, int n_in,
                              void* d_out, int out_size, void* d_ws, size_t ws_size,
                              hipStream_t stream) {
  const float* x = (const float*)d_in[0];
  float* out = (float*)d_out;
  int N = in_sizes[0] / ITEMF;
  int grid = (N + 3) / 4;   // 4 waves/block, 1 item/wave
  yolo_post<<<grid, 256, 0, stream>>>(x, out, N);
}